// Round 2
// baseline (892.888 us; speedup 1.0000x reference)
//
#include <hip/hip_runtime.h>

#define NM 50000
#define HD 128
#define KNEI 8
#define BM 32
#define NH ((size_t)NM * (size_t)HD)

__device__ __forceinline__ float sigm_f(float x) {
    return __builtin_amdgcn_rcpf(1.0f + __expf(-x));
}
__device__ __forceinline__ float tanh_f(float x) {
    return 2.0f * sigm_f(2.0f * x) - 1.0f;
}

// C[m][g] = epilogue( sum_e A[m][e] * W[g][woff+e] )   for e in [0,128)
// MODE 0: C = A@W.T + bias
// MODE 1: C = sigmoid(pre + A@W.T)                       (z gate)
// MODE 2: ph = tanh(pre + A@W.T); C = mask*((1-z)*sumh + z*ph)  (GRU update)
template<int MODE>
__global__ __launch_bounds__(256, 2)
void dgru_gemm(const float* __restrict__ A, const float* __restrict__ W,
               int ldw, int woff,
               const float* __restrict__ bias, const float* __restrict__ pre,
               const float* __restrict__ zbuf, const float* __restrict__ sumh,
               float* __restrict__ C)
{
    __shared__ float Wt[HD][HD];   // Wt[e][g] = W[g][woff+e]
    __shared__ float As[BM][HD];   // As[r][e]
    const int tid  = threadIdx.x;
    const int row0 = blockIdx.x * BM;

    // Load W transposed: thread t -> row g=t/2, e-half (t&1)*64
    {
        const int g  = tid >> 1;
        const int e0 = (tid & 1) << 6;
        const float* wp = W + (size_t)g * ldw + woff + e0;
        #pragma unroll
        for (int j = 0; j < 64; j += 4) {
            const float4 w = *(const float4*)(wp + j);
            Wt[e0 + j + 0][g] = w.x;
            Wt[e0 + j + 1][g] = w.y;
            Wt[e0 + j + 2][g] = w.z;
            Wt[e0 + j + 3][g] = w.w;
        }
    }
    // Load A tile row-major: thread t -> row r=t/8, 16-float chunk (t&7)*16
    {
        const int r  = tid >> 3;
        const int e0 = (tid & 7) << 4;
        int gr = row0 + r; if (gr >= NM) gr = NM - 1;   // clamp; OOB rows never stored
        const float* ap = A + (size_t)gr * HD + e0;
        #pragma unroll
        for (int j = 0; j < 16; j += 4)
            *(float4*)&As[r][e0 + j] = *(const float4*)(ap + j);
    }
    __syncthreads();

    const int c0 = (tid & 31) << 2;   // output col group (0..124)
    const int r0 = (tid >> 5) << 2;   // row group within tile (0..28)
    float acc[4][4];
    #pragma unroll
    for (int i = 0; i < 4; ++i)
        #pragma unroll
        for (int j = 0; j < 4; ++j) acc[i][j] = 0.0f;

    #pragma unroll 4
    for (int e = 0; e < HD; ++e) {
        const float4 w = *(const float4*)&Wt[e][c0];
        #pragma unroll
        for (int i = 0; i < 4; ++i) {
            const float a = As[r0 + i][e];
            acc[i][0] = fmaf(a, w.x, acc[i][0]);
            acc[i][1] = fmaf(a, w.y, acc[i][1]);
            acc[i][2] = fmaf(a, w.z, acc[i][2]);
            acc[i][3] = fmaf(a, w.w, acc[i][3]);
        }
    }

    float4 bv = make_float4(0.f, 0.f, 0.f, 0.f);
    if (MODE == 0 && bias) bv = *(const float4*)&bias[c0];

    #pragma unroll
    for (int i = 0; i < 4; ++i) {
        const int r = row0 + r0 + i;
        if (r >= NM) break;
        const size_t off = (size_t)r * HD + c0;
        float4 o;
        if (MODE == 0) {
            o = make_float4(acc[i][0] + bv.x, acc[i][1] + bv.y,
                            acc[i][2] + bv.z, acc[i][3] + bv.w);
        } else if (MODE == 1) {
            const float4 p = *(const float4*)&pre[off];
            o = make_float4(sigm_f(p.x + acc[i][0]), sigm_f(p.y + acc[i][1]),
                            sigm_f(p.z + acc[i][2]), sigm_f(p.w + acc[i][3]));
        } else {
            const float4 p  = *(const float4*)&pre[off];
            const float4 z4 = *(const float4*)&zbuf[off];
            const float4 s4 = *(const float4*)&sumh[off];
            const float ph0 = tanh_f(p.x + acc[i][0]);
            const float ph1 = tanh_f(p.y + acc[i][1]);
            const float ph2 = tanh_f(p.z + acc[i][2]);
            const float ph3 = tanh_f(p.w + acc[i][3]);
            o = make_float4((1.0f - z4.x) * s4.x + z4.x * ph0,
                            (1.0f - z4.y) * s4.y + z4.y * ph1,
                            (1.0f - z4.z) * s4.z + z4.z * ph2,
                            (1.0f - z4.w) * s4.w + z4.w * ph3);
            if (r == 0) o = make_float4(0.f, 0.f, 0.f, 0.f);  // padding-message mask
        }
        *(float4*)&C[off] = o;
    }
}

// Per message n, dim-chunk d0: sum_h = sum_k h[bg[n][k]]; r_k = sigmoid(pre_r + Uh[bg[n][k]]);
// sum_g = sum_k r_k * h[bg[n][k]].  32 lanes/message (float4 each), 8 messages/block.
__global__ __launch_bounds__(256)
void dgru_gather(const float* __restrict__ h, const float* __restrict__ Uh,
                 const int* __restrict__ bgraph, const float* __restrict__ pre_r,
                 float* __restrict__ sumh, float* __restrict__ sumg)
{
    const int tid = threadIdx.x;
    const int n   = blockIdx.x * 8 + (tid >> 5);
    const int d0  = (tid & 31) << 2;
    if (n >= NM) return;

    int idx[KNEI];
    {
        const int4* bg = (const int4*)(bgraph + (size_t)n * KNEI);
        const int4 b0 = bg[0], b1 = bg[1];
        idx[0] = b0.x; idx[1] = b0.y; idx[2] = b0.z; idx[3] = b0.w;
        idx[4] = b1.x; idx[5] = b1.y; idx[6] = b1.z; idx[7] = b1.w;
    }
    const float4 pr = *(const float4*)&pre_r[(size_t)n * HD + d0];
    float4 sh = make_float4(0.f, 0.f, 0.f, 0.f);
    float4 sg = make_float4(0.f, 0.f, 0.f, 0.f);

    #pragma unroll
    for (int k = 0; k < KNEI; ++k) {
        const size_t o = (size_t)idx[k] * HD + d0;
        const float4 hv = *(const float4*)&h[o];
        const float4 uv = *(const float4*)&Uh[o];
        sh.x += hv.x; sh.y += hv.y; sh.z += hv.z; sh.w += hv.w;
        sg.x = fmaf(sigm_f(pr.x + uv.x), hv.x, sg.x);
        sg.y = fmaf(sigm_f(pr.y + uv.y), hv.y, sg.y);
        sg.z = fmaf(sigm_f(pr.z + uv.z), hv.z, sg.z);
        sg.w = fmaf(sigm_f(pr.w + uv.w), hv.w, sg.w);
    }
    const size_t o = (size_t)n * HD + d0;
    *(float4*)&sumh[o] = sh;
    *(float4*)&sumg[o] = sg;
}

extern "C" void kernel_launch(void* const* d_in, const int* in_sizes, int n_in,
                              void* d_out, int out_size, void* d_ws, size_t ws_size,
                              hipStream_t stream) {
    const float* fmess  = (const float*)d_in[0];
    const int*   bgraph = (const int*)  d_in[1];
    const float* W_z    = (const float*)d_in[2];
    const float* b_z    = (const float*)d_in[3];
    const float* W_r    = (const float*)d_in[4];
    const float* U_r    = (const float*)d_in[5];
    const float* b_Ur   = (const float*)d_in[6];
    const float* W_h    = (const float*)d_in[7];
    const float* b_h    = (const float*)d_in[8];

    float* ws     = (float*)d_ws;
    float* pre_z  = ws;            // fmess@Wz1.T + b_z
    float* pre_r  = ws + NH;       // fmess@W_r.T
    float* pre_hf = ws + 2 * NH;   // fmess@Wh1.T + b_h
    float* Uh     = ws + 3 * NH;   // h@U_r.T + b_Ur; reused as z-buffer
    float* sum_h  = ws + 4 * NH;
    float* sum_g  = ws + 5 * NH;
    float* h      = (float*)d_out; // h lives in d_out across iterations
    // requires ws_size >= 6*NH*4 = 153.6 MB

    const dim3 gblk(256);
    const dim3 ggrid((NM + BM - 1) / BM);   // 1563
    const dim3 sgrid(NM / 8);               // 6250

    // Loop-invariant precompute (fmess halves of the concat matmuls; biases folded in)
    dgru_gemm<0><<<ggrid, gblk, 0, stream>>>(fmess, W_z, 2 * HD, 0, b_z, nullptr, nullptr, nullptr, pre_z);
    dgru_gemm<0><<<ggrid, gblk, 0, stream>>>(fmess, W_r, HD,     0, nullptr, nullptr, nullptr, nullptr, pre_r);
    dgru_gemm<0><<<ggrid, gblk, 0, stream>>>(fmess, W_h, 2 * HD, 0, b_h, nullptr, nullptr, nullptr, pre_hf);

    for (int it = 0; it < 5; ++it) {
        if (it == 0) {
            // h == 0  =>  sum_h = sum_g = 0; skip Uh GEMM and gather
            hipMemsetAsync(sum_h, 0, NH * sizeof(float), stream);
            hipMemsetAsync(sum_g, 0, NH * sizeof(float), stream);
        } else {
            dgru_gemm<0><<<ggrid, gblk, 0, stream>>>(h, U_r, HD, 0, b_Ur, nullptr, nullptr, nullptr, Uh);
            dgru_gather<<<sgrid, gblk, 0, stream>>>(h, Uh, bgraph, pre_r, sum_h, sum_g);
        }
        // z = sigmoid(pre_z + sum_h @ Wz2.T)   (Wz2 = W_z[:,128:256]); written into Uh buffer
        dgru_gemm<1><<<ggrid, gblk, 0, stream>>>(sum_h, W_z, 2 * HD, HD, nullptr, pre_z, nullptr, nullptr, Uh);
        // ph = tanh(pre_hf + sum_g @ Wh2.T); h = mask*((1-z)*sum_h + z*ph)
        dgru_gemm<2><<<ggrid, gblk, 0, stream>>>(sum_g, W_h, 2 * HD, HD, nullptr, pre_hf, Uh, sum_h, h);
    }
}